// Round 18
// baseline (322.473 us; speedup 1.0000x reference)
//
#include <hip/hip_runtime.h>

typedef __attribute__((ext_vector_type(8))) short short8;
typedef __attribute__((ext_vector_type(4))) float f32x4;

constexpr int T_STEPS = 32;
constexpr int BATCH   = 32;
constexpr int DG      = 256;
constexpr int DH      = 512;
constexpr int NHIST   = 31;
constexpr int LDH     = 528;    // area_bf row stride (u16)
constexpr int LDT     = 32;     // histT row stride (u16): 64 B, 2-way-free
constexpr float LAMBDA_ = 0.95f;
constexpr float ETA_    = 0.5f;
constexpr float EPS_    = 1e-5f;

__device__ __forceinline__ uint bf16cvt(float f) {
  uint u = __float_as_uint(f);
  return (u + 0x7FFFu + ((u >> 16) & 1u)) >> 16;
}
__device__ __forceinline__ uint pack2(float a, float b) {
  return bf16cvt(a) | (bf16cvt(b) << 16);
}
__device__ __forceinline__ float bf2f(ushort u) {
  return __uint_as_float(((uint)u) << 16);
}

// Raw barrier: drains LDS (lgkmcnt) for cross-wave visibility but NOT vmcnt,
// so staged global_load_lds ops stay in flight across phases 2-4.
// (Round-15-proven correct: passed refcheck with this exact barrier.)
__device__ __forceinline__ void block_barrier() {
  __builtin_amdgcn_sched_barrier(0);
  asm volatile("s_waitcnt lgkmcnt(0)" ::: "memory");
  __builtin_amdgcn_s_barrier();
  __builtin_amdgcn_sched_barrier(0);
}

// pack: W_h fp32 -> bf16 MFMA A-fragment layout.
// Wp[(mt*16+kk)*64 + lane] = uint4 of 8 bf16 =
//   W[mt*16 + (lane&15)][kk*32 + (lane>>4)*8 .. +8)
__global__ __launch_bounds__(512) void pack_kernel(
    const float* __restrict__ Wh, uint4* __restrict__ Wp) {
  const int f  = blockIdx.x * 512 + threadIdx.x;   // 0..32767
  const int lf = f & 63;
  const int kk = (f >> 6) & 15;
  const int mt = f >> 10;
  const int r  = mt * 16 + (lf & 15);
  const int k0 = kk * 32 + (lf >> 4) * 8;
  const float4 a = *reinterpret_cast<const float4*>(Wh + (size_t)r * DH + k0);
  const float4 b = *reinterpret_cast<const float4*>(Wh + (size_t)r * DH + k0 + 4);
  Wp[f] = make_uint4(pack2(a.x, a.y), pack2(a.z, a.w),
                     pack2(b.x, b.y), pack2(b.z, b.w));
}

// Serial recurrence: 32 self-contained blocks x 512 threads, one batch each.
// Phase 1 consumes W from a 2-slot global_load_lds ring; the next step's
// first 2 columns are issued at the tail of phase 1 and DRAIN ACROSS
// phases 2-4 (raw barriers never drain vmcnt) — the vmem port stays busy
// during the serial LN/dots window instead of idling.
__global__ __launch_bounds__(512, 2) void rnn_kernel(
    const uint4* __restrict__ Wp, const float* __restrict__ z,
    const float* __restrict__ Wg, const float* __restrict__ bh,
    const float* __restrict__ g, const float* __restrict__ be,
    float* __restrict__ out) {
  __shared__ uint4  stage[8][2][4][64];      // 64 KB: wave-private W ring
  __shared__ ushort area_bf[T_STEPS][LDH];   // 33 KB: zg[t] -> hist[t] (bf16)
  __shared__ ushort histT[DH][LDT];          // 32 KB: transposed history (Ah)
  __shared__ float  part[DH];
  __shared__ float  h_s[DH];
  __shared__ ushort hbf[DH];
  __shared__ float  red1[8], red2[8];
  __shared__ float  cc[NHIST + 1];
  __shared__ float  lam_pow[NHIST];

  const int tid  = threadIdx.x;            // 0..511
  const int lane = tid & 63;
  const int wave = tid >> 6;               // 0..7
  const int c    = lane & 15;              // mfma col
  const int gq   = lane >> 4;              // mfma k-group / row-quad
  const int b    = blockIdx.x;             // batch == block
  const int r    = tid;                    // owned row

  if (tid == 0) {
    float p = 1.f;
    for (int k = 0; k < NHIST; ++k) { lam_pow[k] = p; p *= LAMBDA_; }
  }
  if (tid < NHIST + 1) cc[tid] = 0.f;      // slots >= t stay 0 -> no Ah guards
  {                                         // zero own histT row (NaN guard)
    uint4 zz = make_uint4(0u, 0u, 0u, 0u);
#pragma unroll
    for (int i = 0; i < 4; ++i)
      reinterpret_cast<uint4*>(&histT[r][0])[i] = zz;
  }

  // async stage of one kk-column (4 tiles) into stage[wave][slot]
  auto STAGE = [&](int kk, int slot) {
#pragma unroll
    for (int mt4 = 0; mt4 < 4; ++mt4) {
      const uint4* gsrc = Wp + (size_t)((wave * 4 + mt4) * 16 + kk) * 64 + lane;
      __builtin_amdgcn_global_load_lds(
          (const __attribute__((address_space(1))) uint*)gsrc,
          (__attribute__((address_space(3))) uint*)&stage[wave][slot][mt4][0],
          16, 0, 0);
    }
  };

  // ---- Prologue: area_bf[t][:] = bf16(z_b @ Wg^T) (MFMA; cols = t) ----
#pragma unroll
  for (int mt4 = 0; mt4 < 4; ++mt4) {
    const int mt = wave * 4 + mt4;          // 32 M-tiles over DH=512
    f32x4 acc0 = {0.f,0.f,0.f,0.f}, acc1 = {0.f,0.f,0.f,0.f};
#pragma unroll
    for (int kk = 0; kk < 8; ++kk) {        // K = 256
      const int k0 = kk * 32 + gq * 8;
      const float4 a  = *reinterpret_cast<const float4*>(Wg + (size_t)(mt*16 + c) * DG + k0);
      const float4 a2 = *reinterpret_cast<const float4*>(Wg + (size_t)(mt*16 + c) * DG + k0 + 4);
      const uint4 afu = make_uint4(pack2(a.x,a.y), pack2(a.z,a.w),
                                   pack2(a2.x,a2.y), pack2(a2.z,a2.w));
      const float* zb0 = z + ((size_t)c        * BATCH + b) * DG + k0;  // t = c
      const float* zb1 = z + ((size_t)(16 + c) * BATCH + b) * DG + k0;  // t = 16+c
      const float4 b00 = *reinterpret_cast<const float4*>(zb0);
      const float4 b01 = *reinterpret_cast<const float4*>(zb0 + 4);
      const float4 b10 = *reinterpret_cast<const float4*>(zb1);
      const float4 b11 = *reinterpret_cast<const float4*>(zb1 + 4);
      const uint4 bf0 = make_uint4(pack2(b00.x,b00.y), pack2(b00.z,b00.w),
                                   pack2(b01.x,b01.y), pack2(b01.z,b01.w));
      const uint4 bf1 = make_uint4(pack2(b10.x,b10.y), pack2(b10.z,b10.w),
                                   pack2(b11.x,b11.y), pack2(b11.z,b11.w));
      acc0 = __builtin_amdgcn_mfma_f32_16x16x32_bf16(
          __builtin_bit_cast(short8, afu), __builtin_bit_cast(short8, bf0), acc0, 0,0,0);
      acc1 = __builtin_amdgcn_mfma_f32_16x16x32_bf16(
          __builtin_bit_cast(short8, afu), __builtin_bit_cast(short8, bf1), acc1, 0,0,0);
    }
    // D: col=lane&15 -> t, rows mt*16 + gq*4 + 0..3
    *reinterpret_cast<uint2*>(&area_bf[c][mt*16 + gq*4]) =
        make_uint2(pack2(acc0.x, acc0.y), pack2(acc0.z, acc0.w));
    *reinterpret_cast<uint2*>(&area_bf[16 + c][mt*16 + gq*4]) =
        make_uint2(pack2(acc1.x, acc1.y), pack2(acc1.z, acc1.w));
  }
  const float bh_r = bh[r], g_r = g[r], be_r = be[r];
  __syncthreads();              // full drain once; ring discipline starts now

  STAGE(0, 0); STAGE(1, 1);     // prestage for t=1; drains during t=0 phases

  // LayerNorm+ReLU over 512 thread-held scalars; 2 raw barriers.
  auto ln = [&](float x) -> float {
    float s1 = x, s2 = x * x;
#pragma unroll
    for (int off = 32; off; off >>= 1) {
      s1 += __shfl_xor(s1, off, 64);
      s2 += __shfl_xor(s2, off, 64);
    }
    if (lane == 0) { red1[wave] = s1; red2[wave] = s2; }
    block_barrier();
    float a = 0.f, q = 0.f;
#pragma unroll
    for (int w2 = 0; w2 < 8; ++w2) { a += red1[w2]; q += red2[w2]; }
    const float mu = a * (1.f / DH);
    const float rs = rsqrtf(q * (1.f / DH) - mu * mu + EPS_);
    const float hv2 = fmaxf((x - mu) * rs * g_r + be_r, 0.f);
    h_s[r] = hv2;
    hbf[r] = (ushort)bf16cvt(hv2);
    block_barrier();
    return hv2;
  };

  float hv = 0.f;
  for (int t = 0; t < T_STEPS; ++t) {
    float xb;
    if (t == 0) {
      xb = bf2f(area_bf[0][r]) + bh_r;     // h==0: hb = zg
    } else {
      // Phase 1: hb = Wh.h via MFMA, uniform 2-slot ring:
      //   wait vmcnt(4) -> consume slot kk&1 (col kk) -> issue col (kk+2)&15.
      // At kk=14,15 the issues are NEXT step's cols 0,1 (drain over phases).
      f32x4 acc[4] = {{0.f,0.f,0.f,0.f},{0.f,0.f,0.f,0.f},
                      {0.f,0.f,0.f,0.f},{0.f,0.f,0.f,0.f}};
      uint4 bfr[8];
#pragma unroll
      for (int j = 0; j < 8; ++j)
        bfr[j] = *reinterpret_cast<const uint4*>(&hbf[j*32 + gq*8]);
#pragma unroll
      for (int kk = 0; kk < 16; ++kk) {
        if (kk == 8) {
#pragma unroll
          for (int j = 0; j < 8; ++j)
            bfr[j] = *reinterpret_cast<const uint4*>(&hbf[(j + 8)*32 + gq*8]);
        }
        asm volatile("s_waitcnt vmcnt(4)" ::: "memory");
        __builtin_amdgcn_sched_barrier(0);
        const int slot = kk & 1;
        const uint4 a0 = stage[wave][slot][0][lane];
        const uint4 a1 = stage[wave][slot][1][lane];
        const uint4 a2 = stage[wave][slot][2][lane];
        const uint4 a3 = stage[wave][slot][3][lane];
        const short8 bv = __builtin_bit_cast(short8, bfr[kk & 7]);
        acc[0] = __builtin_amdgcn_mfma_f32_16x16x32_bf16(
            __builtin_bit_cast(short8, a0), bv, acc[0], 0,0,0);
        acc[1] = __builtin_amdgcn_mfma_f32_16x16x32_bf16(
            __builtin_bit_cast(short8, a1), bv, acc[1], 0,0,0);
        acc[2] = __builtin_amdgcn_mfma_f32_16x16x32_bf16(
            __builtin_bit_cast(short8, a2), bv, acc[2], 0,0,0);
        acc[3] = __builtin_amdgcn_mfma_f32_16x16x32_bf16(
            __builtin_bit_cast(short8, a3), bv, acc[3], 0,0,0);
        STAGE((kk + 2) & 15, slot);        // refill just-consumed slot
      }
      if (c == 0) {
#pragma unroll
        for (int mt4 = 0; mt4 < 4; ++mt4)
          *reinterpret_cast<f32x4*>(&part[(wave*4 + mt4)*16 + gq*4]) = acc[mt4];
      }
      block_barrier();                                   // B1 (no vmcnt drain)
      xb = part[r] + bf2f(area_bf[t][r]) + bh_r;
    }

    // Phase 2: h = relu(LN(hb))
    hv = ln(xb);

    // Phase 3: S_LOOP=2 fast-weight reads (A==0 at t=0 -> skip)
    if (t > 0) {
      for (int s = 0; s < 2; ++s) {
        // cc[sp] = ETA*lambda^(t-1-sp) * (hist[sp] . h); bf16 rows, b128 reads
        const float4 c0 = *reinterpret_cast<const float4*>(&h_s[lane * 8]);
        const float4 c1 = *reinterpret_cast<const float4*>(&h_s[lane * 8 + 4]);
        for (int sp = wave; sp < t; sp += 8) {
          const uint4 hw = *reinterpret_cast<const uint4*>(&area_bf[sp][lane * 8]);
          float d;
          d =      __uint_as_float(hw.x << 16)          * c0.x;
          d = fmaf(__uint_as_float(hw.x & 0xFFFF0000u), c0.y, d);
          d = fmaf(__uint_as_float(hw.y << 16),         c0.z, d);
          d = fmaf(__uint_as_float(hw.y & 0xFFFF0000u), c0.w, d);
          d = fmaf(__uint_as_float(hw.z << 16),         c1.x, d);
          d = fmaf(__uint_as_float(hw.z & 0xFFFF0000u), c1.y, d);
          d = fmaf(__uint_as_float(hw.w << 16),         c1.z, d);
          d = fmaf(__uint_as_float(hw.w & 0xFFFF0000u), c1.w, d);
#pragma unroll
          for (int off = 32; off; off >>= 1) d += __shfl_xor(d, off, 64);
          if (lane == 0) cc[sp] = ETA_ * lam_pow[t - 1 - sp] * d;
        }
        block_barrier();                                  // B4
        // Ah from own-thread transposed bf16 history row: 4 x b128 + 32 fmaf
        float ah = 0.f;
#pragma unroll
        for (int q8 = 0; q8 < 4; ++q8) {
          const uint4 hw = *reinterpret_cast<const uint4*>(&histT[r][q8 * 8]);
          const uint w0 = hw.x, w1 = hw.y, w2 = hw.z, w3 = hw.w;
          ah = fmaf(cc[q8*8+0], __uint_as_float(w0 << 16),          ah);
          ah = fmaf(cc[q8*8+1], __uint_as_float(w0 & 0xFFFF0000u),  ah);
          ah = fmaf(cc[q8*8+2], __uint_as_float(w1 << 16),          ah);
          ah = fmaf(cc[q8*8+3], __uint_as_float(w1 & 0xFFFF0000u),  ah);
          ah = fmaf(cc[q8*8+4], __uint_as_float(w2 << 16),          ah);
          ah = fmaf(cc[q8*8+5], __uint_as_float(w2 & 0xFFFF0000u),  ah);
          ah = fmaf(cc[q8*8+6], __uint_as_float(w3 << 16),          ah);
          ah = fmaf(cc[q8*8+7], __uint_as_float(w3 & 0xFFFF0000u),  ah);
        }
        hv = ln(xb + ah);
      }
    }

    // Phase 4: hist[t] := h (area_bf row for dots; own histT row for Ah —
    // same-thread write/read, needs no barrier)
    if (t < T_STEPS - 1) {
      const ushort h16 = (ushort)bf16cvt(hv);
      area_bf[t][r] = h16;
      histT[r][t]   = h16;
    }
  }

  out[(size_t)b * DH + r] = hv;
}

extern "C" void kernel_launch(void* const* d_in, const int* in_sizes, int n_in,
                              void* d_out, int out_size, void* d_ws, size_t ws_size,
                              hipStream_t stream) {
  const float* z     = (const float*)d_in[0];  // [T,B,DG]
  const float* W_h   = (const float*)d_in[1];  // [DH,DH]
  const float* W_g   = (const float*)d_in[2];  // [DH,DG]
  const float* b_h   = (const float*)d_in[3];  // [DH]
  const float* gamma = (const float*)d_in[4];  // [DH]
  const float* beta  = (const float*)d_in[5];  // [DH]
  float* out = (float*)d_out;                  // [B,DH]

  uint4* Wp = (uint4*)d_ws;                    // 512 KB packed W_h

  pack_kernel<<<dim3(64), dim3(512), 0, stream>>>(W_h, Wp);
  rnn_kernel<<<dim3(BATCH), dim3(512), 0, stream>>>(Wp, z, W_g, b_h,
                                                    gamma, beta, out);
}

// Round 19
// 305.980 us; speedup vs baseline: 1.0539x; 1.0539x over previous
//
#include <hip/hip_runtime.h>

typedef __attribute__((ext_vector_type(8))) short short8;
typedef __attribute__((ext_vector_type(4))) float f32x4;

constexpr int T_STEPS = 32;
constexpr int BATCH   = 32;
constexpr int DG      = 256;
constexpr int DH      = 512;
constexpr int NHIST   = 31;
constexpr int LDH     = 528;    // area_bf row stride (u16): 1056 B
constexpr int RKK     = 3;      // resident W kk-columns (96 KB LDS)
constexpr float LAMBDA_ = 0.95f;
constexpr float ETA_    = 0.5f;
constexpr float EPS_    = 1e-5f;

__device__ __forceinline__ uint bf16cvt(float f) {
  uint u = __float_as_uint(f);
  return (u + 0x7FFFu + ((u >> 16) & 1u)) >> 16;
}
__device__ __forceinline__ uint pack2(float a, float b) {
  return bf16cvt(a) | (bf16cvt(b) << 16);
}
__device__ __forceinline__ float bf2f(ushort u) {
  return __uint_as_float(((uint)u) << 16);
}

// pack: W_h fp32 -> bf16 MFMA A-fragment layout.
// Wp[(mt*16+kk)*64 + lane] = uint4 of 8 bf16 =
//   W[mt*16 + (lane&15)][kk*32 + (lane>>4)*8 .. +8)
__global__ __launch_bounds__(512) void pack_kernel(
    const float* __restrict__ Wh, uint4* __restrict__ Wp) {
  const int f  = blockIdx.x * 512 + threadIdx.x;   // 0..32767
  const int lf = f & 63;
  const int kk = (f >> 6) & 15;
  const int mt = f >> 10;
  const int r  = mt * 16 + (lf & 15);
  const int k0 = kk * 32 + (lf >> 4) * 8;
  const float4 a = *reinterpret_cast<const float4*>(Wh + (size_t)r * DH + k0);
  const float4 b = *reinterpret_cast<const float4*>(Wh + (size_t)r * DH + k0 + 4);
  Wp[f] = make_uint4(pack2(a.x, a.y), pack2(a.z, a.w),
                     pack2(b.x, b.y), pack2(b.z, b.w));
}

// Serial recurrence: 32 self-contained blocks x 512 threads, one batch each.
// Stream-byte-reduction maximized: W kk=0..2 (96 KB) resident in LDS
// (separate ds_read pipe), stream = 416 KB/step (was 512 in R16, 448 in R17).
// histT dropped to make room; Ah = scalar u16 gather from area_bf rows
// (runtime sp<t bound; consecutive-lane u16 = 2-way banked, free).
__global__ __launch_bounds__(512, 2) void rnn_kernel(
    const uint4* __restrict__ Wp, const float* __restrict__ z,
    const float* __restrict__ Wg, const float* __restrict__ bh,
    const float* __restrict__ g, const float* __restrict__ be,
    float* __restrict__ out) {
  __shared__ uint4  Wres[RKK * 32 * 64];     // 96 KB: W kk=0..2 fragments
  __shared__ ushort area_bf[T_STEPS][LDH];   // 33 KB: zg[t] -> hist[t] (bf16)
  __shared__ float  part[DH];
  __shared__ float  h_s[DH];
  __shared__ ushort hbf[DH];
  __shared__ float  red1[8], red2[8];
  __shared__ float  cc[NHIST + 1];
  __shared__ float  lam_pow[NHIST];

  const int tid  = threadIdx.x;            // 0..511
  const int lane = tid & 63;
  const int wave = tid >> 6;               // 0..7
  const int c    = lane & 15;              // mfma col
  const int gq   = lane >> 4;              // mfma k-group / row-quad
  const int b    = blockIdx.x;             // batch == block
  const int r    = tid;                    // owned row

  if (tid == 0) {
    float p = 1.f;
    for (int k = 0; k < NHIST; ++k) { lam_pow[k] = p; p *= LAMBDA_; }
  }
  if (tid < NHIST + 1) cc[tid] = 0.f;

  // ---- Copy resident W (kk=0..RKK-1, all 32 M-tiles) into LDS ----
  // Layout: Wres[(mt*RKK + kk)*64 + ln2]
#pragma unroll
  for (int kkl = 0; kkl < RKK; ++kkl) {
#pragma unroll
    for (int i2 = 0; i2 < 4; ++i2) {
      const int f2  = i2 * 512 + tid;       // 0..2047 = mt*64 + ln2
      const int mt  = f2 >> 6;
      const int ln2 = f2 & 63;
      Wres[(mt * RKK + kkl) * 64 + ln2] = Wp[(size_t)(mt * 16 + kkl) * 64 + ln2];
    }
  }

  // ---- Prologue: area_bf[t][:] = bf16(z_b @ Wg^T) (MFMA; cols = t) ----
#pragma unroll
  for (int mt4 = 0; mt4 < 4; ++mt4) {
    const int mt = wave * 4 + mt4;          // 32 M-tiles over DH=512
    f32x4 acc0 = {0.f,0.f,0.f,0.f}, acc1 = {0.f,0.f,0.f,0.f};
#pragma unroll
    for (int kk = 0; kk < 8; ++kk) {        // K = 256
      const int k0 = kk * 32 + gq * 8;
      const float4 a  = *reinterpret_cast<const float4*>(Wg + (size_t)(mt*16 + c) * DG + k0);
      const float4 a2 = *reinterpret_cast<const float4*>(Wg + (size_t)(mt*16 + c) * DG + k0 + 4);
      const uint4 afu = make_uint4(pack2(a.x,a.y), pack2(a.z,a.w),
                                   pack2(a2.x,a2.y), pack2(a2.z,a2.w));
      const float* zb0 = z + ((size_t)c        * BATCH + b) * DG + k0;  // t = c
      const float* zb1 = z + ((size_t)(16 + c) * BATCH + b) * DG + k0;  // t = 16+c
      const float4 b00 = *reinterpret_cast<const float4*>(zb0);
      const float4 b01 = *reinterpret_cast<const float4*>(zb0 + 4);
      const float4 b10 = *reinterpret_cast<const float4*>(zb1);
      const float4 b11 = *reinterpret_cast<const float4*>(zb1 + 4);
      const uint4 bf0 = make_uint4(pack2(b00.x,b00.y), pack2(b00.z,b00.w),
                                   pack2(b01.x,b01.y), pack2(b01.z,b01.w));
      const uint4 bf1 = make_uint4(pack2(b10.x,b10.y), pack2(b10.z,b10.w),
                                   pack2(b11.x,b11.y), pack2(b11.z,b11.w));
      acc0 = __builtin_amdgcn_mfma_f32_16x16x32_bf16(
          __builtin_bit_cast(short8, afu), __builtin_bit_cast(short8, bf0), acc0, 0,0,0);
      acc1 = __builtin_amdgcn_mfma_f32_16x16x32_bf16(
          __builtin_bit_cast(short8, afu), __builtin_bit_cast(short8, bf1), acc1, 0,0,0);
    }
    // D: col=lane&15 -> t, rows mt*16 + gq*4 + 0..3
    *reinterpret_cast<uint2*>(&area_bf[c][mt*16 + gq*4]) =
        make_uint2(pack2(acc0.x, acc0.y), pack2(acc0.z, acc0.w));
    *reinterpret_cast<uint2*>(&area_bf[16 + c][mt*16 + gq*4]) =
        make_uint2(pack2(acc1.x, acc1.y), pack2(acc1.z, acc1.w));
  }
  __syncthreads();

  const float bh_r = bh[r], g_r = g[r], be_r = be[r];

  // LayerNorm+ReLU over 512 thread-held scalars; 2 barriers; writes h_s+hbf.
  auto ln = [&](float x) -> float {
    float s1 = x, s2 = x * x;
#pragma unroll
    for (int off = 32; off; off >>= 1) {
      s1 += __shfl_xor(s1, off, 64);
      s2 += __shfl_xor(s2, off, 64);
    }
    if (lane == 0) { red1[wave] = s1; red2[wave] = s2; }
    __syncthreads();
    float a = 0.f, q = 0.f;
#pragma unroll
    for (int w2 = 0; w2 < 8; ++w2) { a += red1[w2]; q += red2[w2]; }
    const float mu = a * (1.f / DH);
    const float rs = rsqrtf(q * (1.f / DH) - mu * mu + EPS_);
    const float hv2 = fmaxf((x - mu) * rs * g_r + be_r, 0.f);
    h_s[r] = hv2;
    hbf[r] = (ushort)bf16cvt(hv2);
    __syncthreads();
    return hv2;
  };

  float hv = 0.f;
  for (int t = 0; t < T_STEPS; ++t) {
    float xb;
    if (t == 0) {
      xb = bf2f(area_bf[0][r]) + bh_r;     // h==0: hb = zg
    } else {
      // Phase 1: hb = Wh.h via MFMA. kk=0..2 from LDS (ds_read pipe,
      // overlaps the global stream); kk=3..15 streamed from L2 (416 KB/step).
      f32x4 acc[4] = {{0.f,0.f,0.f,0.f},{0.f,0.f,0.f,0.f},
                      {0.f,0.f,0.f,0.f},{0.f,0.f,0.f,0.f}};
      uint4 bfr[8];
#pragma unroll
      for (int kk = 0; kk < 8; ++kk)
        bfr[kk] = *reinterpret_cast<const uint4*>(&hbf[kk*32 + gq*8]);
      // resident kk=0..2
#pragma unroll
      for (int kk = 0; kk < RKK; ++kk) {
        const short8 bv = __builtin_bit_cast(short8, bfr[kk]);
#pragma unroll
        for (int mt4 = 0; mt4 < 4; ++mt4) {
          const uint4 au = Wres[((wave*4 + mt4)*RKK + kk) * 64 + lane];
          acc[mt4] = __builtin_amdgcn_mfma_f32_16x16x32_bf16(
              __builtin_bit_cast(short8, au), bv, acc[mt4], 0,0,0);
        }
      }
      // streamed kk=3..7
#pragma unroll
      for (int kk = RKK; kk < 8; ++kk) {
        const short8 bv = __builtin_bit_cast(short8, bfr[kk]);
#pragma unroll
        for (int mt4 = 0; mt4 < 4; ++mt4) {
          const uint4 au = Wp[(size_t)((wave*4 + mt4)*16 + kk) * 64 + lane];
          acc[mt4] = __builtin_amdgcn_mfma_f32_16x16x32_bf16(
              __builtin_bit_cast(short8, au), bv, acc[mt4], 0,0,0);
        }
      }
      // streamed kk=8..15
#pragma unroll
      for (int kk = 0; kk < 8; ++kk)
        bfr[kk] = *reinterpret_cast<const uint4*>(&hbf[(kk + 8)*32 + gq*8]);
#pragma unroll
      for (int kk = 8; kk < 16; ++kk) {
        const short8 bv = __builtin_bit_cast(short8, bfr[kk - 8]);
#pragma unroll
        for (int mt4 = 0; mt4 < 4; ++mt4) {
          const uint4 au = Wp[(size_t)((wave*4 + mt4)*16 + kk) * 64 + lane];
          acc[mt4] = __builtin_amdgcn_mfma_f32_16x16x32_bf16(
              __builtin_bit_cast(short8, au), bv, acc[mt4], 0,0,0);
        }
      }
      if (c == 0) {
#pragma unroll
        for (int mt4 = 0; mt4 < 4; ++mt4)
          *reinterpret_cast<f32x4*>(&part[(wave*4 + mt4)*16 + gq*4]) = acc[mt4];
      }
      __syncthreads();                                   // B1
      xb = part[r] + bf2f(area_bf[t][r]) + bh_r;
    }

    // Phase 2: h = relu(LN(hb))
    hv = ln(xb);                                          // B2,B3

    // Phase 3: S_LOOP=2 fast-weight reads (A==0 at t=0 -> skip)
    if (t > 0) {
      for (int s = 0; s < 2; ++s) {
        // cc[sp] = ETA*lambda^(t-1-sp) * (hist[sp] . h); bf16 rows, b128 reads
        const float4 c0 = *reinterpret_cast<const float4*>(&h_s[lane * 8]);
        const float4 c1 = *reinterpret_cast<const float4*>(&h_s[lane * 8 + 4]);
        for (int sp = wave; sp < t; sp += 8) {
          const uint4 hw = *reinterpret_cast<const uint4*>(&area_bf[sp][lane * 8]);
          float d;
          d =      __uint_as_float(hw.x << 16)          * c0.x;
          d = fmaf(__uint_as_float(hw.x & 0xFFFF0000u), c0.y, d);
          d = fmaf(__uint_as_float(hw.y << 16),         c0.z, d);
          d = fmaf(__uint_as_float(hw.y & 0xFFFF0000u), c0.w, d);
          d = fmaf(__uint_as_float(hw.z << 16),         c1.x, d);
          d = fmaf(__uint_as_float(hw.z & 0xFFFF0000u), c1.y, d);
          d = fmaf(__uint_as_float(hw.w << 16),         c1.z, d);
          d = fmaf(__uint_as_float(hw.w & 0xFFFF0000u), c1.w, d);
#pragma unroll
          for (int off = 32; off; off >>= 1) d += __shfl_xor(d, off, 64);
          if (lane == 0) cc[sp] = ETA_ * lam_pow[t - 1 - sp] * d;
        }
        __syncthreads();                                  // B4
        // Ah: scalar u16 gather down area_bf column r (runtime sp<t bound;
        // consecutive lanes read consecutive u16 -> 2-way banked, free)
        float ah = 0.f;
        for (int sp = 0; sp < t; ++sp)
          ah = fmaf(cc[sp], bf2f(area_bf[sp][r]), ah);
        hv = ln(xb + ah);                                 // B5,B6
      }
    }

    // Phase 4: hist[t] := h (overwrites zg row t, which is now dead)
    if (t < T_STEPS - 1) area_bf[t][r] = (ushort)bf16cvt(hv);
  }

  out[(size_t)b * DH + r] = hv;
}

extern "C" void kernel_launch(void* const* d_in, const int* in_sizes, int n_in,
                              void* d_out, int out_size, void* d_ws, size_t ws_size,
                              hipStream_t stream) {
  const float* z     = (const float*)d_in[0];  // [T,B,DG]
  const float* W_h   = (const float*)d_in[1];  // [DH,DH]
  const float* W_g   = (const float*)d_in[2];  // [DH,DG]
  const float* b_h   = (const float*)d_in[3];  // [DH]
  const float* gamma = (const float*)d_in[4];  // [DH]
  const float* beta  = (const float*)d_in[5];  // [DH]
  float* out = (float*)d_out;                  // [B,DH]

  uint4* Wp = (uint4*)d_ws;                    // 512 KB packed W_h

  pack_kernel<<<dim3(64), dim3(512), 0, stream>>>(W_h, Wp);
  rnn_kernel<<<dim3(BATCH), dim3(512), 0, stream>>>(Wp, z, W_g, b_h,
                                                    gamma, beta, out);
}

// Round 20
// 281.087 us; speedup vs baseline: 1.1472x; 1.0886x over previous
//
#include <hip/hip_runtime.h>

typedef __attribute__((ext_vector_type(8))) short short8;
typedef __attribute__((ext_vector_type(4))) float f32x4;

constexpr int T_STEPS = 32;
constexpr int BATCH   = 32;
constexpr int DG      = 256;
constexpr int DH      = 512;
constexpr int NHIST   = 31;
constexpr int LDH     = 528;    // area_bf row stride (u16): 1056 B, 16B-aligned
constexpr int LDT     = 40;     // histT row stride (u16): 80 B, 16B-aligned
constexpr float LAMBDA_ = 0.95f;
constexpr float ETA_    = 0.5f;
constexpr float EPS_    = 1e-5f;

__device__ __forceinline__ uint bf16cvt(float f) {
  uint u = __float_as_uint(f);
  return (u + 0x7FFFu + ((u >> 16) & 1u)) >> 16;
}
__device__ __forceinline__ uint pack2(float a, float b) {
  return bf16cvt(a) | (bf16cvt(b) << 16);
}
__device__ __forceinline__ float bf2f(ushort u) {
  return __uint_as_float(((uint)u) << 16);
}

// pack: W_h fp32 -> bf16 MFMA A-fragment layout.
// Wp[(mt*16+kk)*64 + lane] = uint4 of 8 bf16 =
//   W[mt*16 + (lane&15)][kk*32 + (lane>>4)*8 .. +8)
__global__ __launch_bounds__(512) void pack_kernel(
    const float* __restrict__ Wh, uint4* __restrict__ Wp) {
  const int f  = blockIdx.x * 512 + threadIdx.x;   // 0..32767
  const int lf = f & 63;
  const int kk = (f >> 6) & 15;
  const int mt = f >> 10;
  const int r  = mt * 16 + (lf & 15);
  const int k0 = kk * 32 + (lf >> 4) * 8;
  const float4 a = *reinterpret_cast<const float4*>(Wh + (size_t)r * DH + k0);
  const float4 b = *reinterpret_cast<const float4*>(Wh + (size_t)r * DH + k0 + 4);
  Wp[f] = make_uint4(pack2(a.x, a.y), pack2(a.z, a.w),
                     pack2(b.x, b.y), pack2(b.z, b.w));
}

// Serial recurrence: 32 self-contained blocks x 512 threads, one batch each.
// ROUND-17 CONFIGURATION (measured optimum over 19 rounds):
// - W kk=0,1 (64 KB) resident in LDS (ds_read pipe overlaps L2 stream);
//   kk=2..15 (448 KB/step) streamed direct L2->VGPR (measured per-CU ingest
//   ~40 B/clk makes this ~4.6 us/step, the dominant floor).
// - zg/history bf16 rows in area_bf (33 KB); dots = b128 reads + shfl reduce.
// - Ah = b128 reads of own-thread transposed histT row (vectorized, no
//   serial ds_read chain — R19 showed the scalar variant costs +0.9 us/step).
__global__ __launch_bounds__(512, 2) void rnn_kernel(
    const uint4* __restrict__ Wp, const float* __restrict__ z,
    const float* __restrict__ Wg, const float* __restrict__ bh,
    const float* __restrict__ g, const float* __restrict__ be,
    float* __restrict__ out) {
  __shared__ uint4  Wres[2 * 32 * 64];       // 64 KB: W kk=0,1 fragments
  __shared__ ushort area_bf[T_STEPS][LDH];   // 33 KB: zg[t] -> hist[t] (bf16)
  __shared__ ushort histT[DH][LDT];          // 40 KB: transposed history (Ah)
  __shared__ float  part[DH];
  __shared__ float  h_s[DH];
  __shared__ ushort hbf[DH];
  __shared__ float  red1[8], red2[8];
  __shared__ float  cc[NHIST + 1];
  __shared__ float  lam_pow[NHIST];

  const int tid  = threadIdx.x;            // 0..511
  const int lane = tid & 63;
  const int wave = tid >> 6;               // 0..7
  const int c    = lane & 15;              // mfma col
  const int gq   = lane >> 4;              // mfma k-group / row-quad
  const int b    = blockIdx.x;             // batch == block
  const int r    = tid;                    // owned row

  if (tid == 0) {
    float p = 1.f;
    for (int k = 0; k < NHIST; ++k) { lam_pow[k] = p; p *= LAMBDA_; }
  }
  if (tid < NHIST + 1) cc[tid] = 0.f;      // slots >= t stay 0 -> no Ah guards
  {                                         // zero own histT row (NaN guard)
    uint4 zz = make_uint4(0u, 0u, 0u, 0u);
#pragma unroll
    for (int i = 0; i < 5; ++i)
      reinterpret_cast<uint4*>(&histT[r][0])[i] = zz;
  }
  // ---- Copy resident W (kk=0,1 for all 32 M-tiles) into LDS ----
#pragma unroll
  for (int i2 = 0; i2 < 8; ++i2) {
    const int i  = i2 * 512 + tid;          // 0..4095
    const int mt = i >> 7, kkl = (i >> 6) & 1, ln2 = i & 63;
    Wres[i] = Wp[(size_t)(mt * 16 + kkl) * 64 + ln2];
  }

  // ---- Prologue: area_bf[t][:] = bf16(z_b @ Wg^T) (MFMA; cols = t) ----
#pragma unroll
  for (int mt4 = 0; mt4 < 4; ++mt4) {
    const int mt = wave * 4 + mt4;          // 32 M-tiles over DH=512
    f32x4 acc0 = {0.f,0.f,0.f,0.f}, acc1 = {0.f,0.f,0.f,0.f};
#pragma unroll
    for (int kk = 0; kk < 8; ++kk) {        // K = 256
      const int k0 = kk * 32 + gq * 8;
      const float4 a  = *reinterpret_cast<const float4*>(Wg + (size_t)(mt*16 + c) * DG + k0);
      const float4 a2 = *reinterpret_cast<const float4*>(Wg + (size_t)(mt*16 + c) * DG + k0 + 4);
      const uint4 afu = make_uint4(pack2(a.x,a.y), pack2(a.z,a.w),
                                   pack2(a2.x,a2.y), pack2(a2.z,a2.w));
      const float* zb0 = z + ((size_t)c        * BATCH + b) * DG + k0;  // t = c
      const float* zb1 = z + ((size_t)(16 + c) * BATCH + b) * DG + k0;  // t = 16+c
      const float4 b00 = *reinterpret_cast<const float4*>(zb0);
      const float4 b01 = *reinterpret_cast<const float4*>(zb0 + 4);
      const float4 b10 = *reinterpret_cast<const float4*>(zb1);
      const float4 b11 = *reinterpret_cast<const float4*>(zb1 + 4);
      const uint4 bf0 = make_uint4(pack2(b00.x,b00.y), pack2(b00.z,b00.w),
                                   pack2(b01.x,b01.y), pack2(b01.z,b01.w));
      const uint4 bf1 = make_uint4(pack2(b10.x,b10.y), pack2(b10.z,b10.w),
                                   pack2(b11.x,b11.y), pack2(b11.z,b11.w));
      acc0 = __builtin_amdgcn_mfma_f32_16x16x32_bf16(
          __builtin_bit_cast(short8, afu), __builtin_bit_cast(short8, bf0), acc0, 0,0,0);
      acc1 = __builtin_amdgcn_mfma_f32_16x16x32_bf16(
          __builtin_bit_cast(short8, afu), __builtin_bit_cast(short8, bf1), acc1, 0,0,0);
    }
    // D: col=lane&15 -> t, rows mt*16 + gq*4 + 0..3
    *reinterpret_cast<uint2*>(&area_bf[c][mt*16 + gq*4]) =
        make_uint2(pack2(acc0.x, acc0.y), pack2(acc0.z, acc0.w));
    *reinterpret_cast<uint2*>(&area_bf[16 + c][mt*16 + gq*4]) =
        make_uint2(pack2(acc1.x, acc1.y), pack2(acc1.z, acc1.w));
  }
  __syncthreads();

  const float bh_r = bh[r], g_r = g[r], be_r = be[r];

  // LayerNorm+ReLU over 512 thread-held scalars; 2 barriers; writes h_s+hbf.
  auto ln = [&](float x) -> float {
    float s1 = x, s2 = x * x;
#pragma unroll
    for (int off = 32; off; off >>= 1) {
      s1 += __shfl_xor(s1, off, 64);
      s2 += __shfl_xor(s2, off, 64);
    }
    if (lane == 0) { red1[wave] = s1; red2[wave] = s2; }
    __syncthreads();
    float a = 0.f, q = 0.f;
#pragma unroll
    for (int w2 = 0; w2 < 8; ++w2) { a += red1[w2]; q += red2[w2]; }
    const float mu = a * (1.f / DH);
    const float rs = rsqrtf(q * (1.f / DH) - mu * mu + EPS_);
    const float hv2 = fmaxf((x - mu) * rs * g_r + be_r, 0.f);
    h_s[r] = hv2;
    hbf[r] = (ushort)bf16cvt(hv2);
    __syncthreads();
    return hv2;
  };

  float hv = 0.f;
  for (int t = 0; t < T_STEPS; ++t) {
    float xb;
    if (t == 0) {
      xb = bf2f(area_bf[0][r]) + bh_r;     // h==0: hb = zg
    } else {
      // Phase 1: hb = Wh.h via MFMA. kk=0,1 from LDS (ds_read pipe, overlaps
      // the global stream); kk=2..15 streamed from L2 (448 KB/step).
      f32x4 acc[4] = {{0.f,0.f,0.f,0.f},{0.f,0.f,0.f,0.f},
                      {0.f,0.f,0.f,0.f},{0.f,0.f,0.f,0.f}};
      uint4 bfr[8];
#pragma unroll
      for (int kk = 0; kk < 8; ++kk)
        bfr[kk] = *reinterpret_cast<const uint4*>(&hbf[kk*32 + gq*8]);
      // resident kk=0,1
#pragma unroll
      for (int kk = 0; kk < 2; ++kk) {
        const short8 bv = __builtin_bit_cast(short8, bfr[kk]);
#pragma unroll
        for (int mt4 = 0; mt4 < 4; ++mt4) {
          const uint4 au = Wres[(size_t)((wave*4 + mt4)*2 + kk) * 64 + lane];
          acc[mt4] = __builtin_amdgcn_mfma_f32_16x16x32_bf16(
              __builtin_bit_cast(short8, au), bv, acc[mt4], 0,0,0);
        }
      }
      // streamed kk=2..7
#pragma unroll
      for (int kk = 2; kk < 8; ++kk) {
        const short8 bv = __builtin_bit_cast(short8, bfr[kk]);
#pragma unroll
        for (int mt4 = 0; mt4 < 4; ++mt4) {
          const uint4 au = Wp[(size_t)((wave*4 + mt4)*16 + kk) * 64 + lane];
          acc[mt4] = __builtin_amdgcn_mfma_f32_16x16x32_bf16(
              __builtin_bit_cast(short8, au), bv, acc[mt4], 0,0,0);
        }
      }
      // streamed kk=8..15
#pragma unroll
      for (int kk = 0; kk < 8; ++kk)
        bfr[kk] = *reinterpret_cast<const uint4*>(&hbf[(kk + 8)*32 + gq*8]);
#pragma unroll
      for (int kk = 8; kk < 16; ++kk) {
        const short8 bv = __builtin_bit_cast(short8, bfr[kk - 8]);
#pragma unroll
        for (int mt4 = 0; mt4 < 4; ++mt4) {
          const uint4 au = Wp[(size_t)((wave*4 + mt4)*16 + kk) * 64 + lane];
          acc[mt4] = __builtin_amdgcn_mfma_f32_16x16x32_bf16(
              __builtin_bit_cast(short8, au), bv, acc[mt4], 0,0,0);
        }
      }
      if (c == 0) {
#pragma unroll
        for (int mt4 = 0; mt4 < 4; ++mt4)
          *reinterpret_cast<f32x4*>(&part[(wave*4 + mt4)*16 + gq*4]) = acc[mt4];
      }
      __syncthreads();                                   // B1
      xb = part[r] + bf2f(area_bf[t][r]) + bh_r;
    }

    // Phase 2: h = relu(LN(hb))
    hv = ln(xb);                                          // B2,B3

    // Phase 3: S_LOOP=2 fast-weight reads (A==0 at t=0 -> skip)
    if (t > 0) {
      for (int s = 0; s < 2; ++s) {
        // cc[sp] = ETA*lambda^(t-1-sp) * (hist[sp] . h); bf16 rows, b128 reads
        const float4 c0 = *reinterpret_cast<const float4*>(&h_s[lane * 8]);
        const float4 c1 = *reinterpret_cast<const float4*>(&h_s[lane * 8 + 4]);
        for (int sp = wave; sp < t; sp += 8) {
          const uint4 hw = *reinterpret_cast<const uint4*>(&area_bf[sp][lane * 8]);
          float d;
          d =      __uint_as_float(hw.x << 16)          * c0.x;
          d = fmaf(__uint_as_float(hw.x & 0xFFFF0000u), c0.y, d);
          d = fmaf(__uint_as_float(hw.y << 16),         c0.z, d);
          d = fmaf(__uint_as_float(hw.y & 0xFFFF0000u), c0.w, d);
          d = fmaf(__uint_as_float(hw.z << 16),         c1.x, d);
          d = fmaf(__uint_as_float(hw.z & 0xFFFF0000u), c1.y, d);
          d = fmaf(__uint_as_float(hw.w << 16),         c1.z, d);
          d = fmaf(__uint_as_float(hw.w & 0xFFFF0000u), c1.w, d);
#pragma unroll
          for (int off = 32; off; off >>= 1) d += __shfl_xor(d, off, 64);
          if (lane == 0) cc[sp] = ETA_ * lam_pow[t - 1 - sp] * d;
        }
        __syncthreads();                                  // B4
        // Ah from own-thread transposed bf16 history row: 4 x b128 + 32 fmaf
        float ah = 0.f;
#pragma unroll
        for (int q8 = 0; q8 < 4; ++q8) {
          const uint4 hw = *reinterpret_cast<const uint4*>(&histT[r][q8 * 8]);
          const uint w0 = hw.x, w1 = hw.y, w2 = hw.z, w3 = hw.w;
          ah = fmaf(cc[q8*8+0], __uint_as_float(w0 << 16),          ah);
          ah = fmaf(cc[q8*8+1], __uint_as_float(w0 & 0xFFFF0000u),  ah);
          ah = fmaf(cc[q8*8+2], __uint_as_float(w1 << 16),          ah);
          ah = fmaf(cc[q8*8+3], __uint_as_float(w1 & 0xFFFF0000u),  ah);
          ah = fmaf(cc[q8*8+4], __uint_as_float(w2 << 16),          ah);
          ah = fmaf(cc[q8*8+5], __uint_as_float(w2 & 0xFFFF0000u),  ah);
          ah = fmaf(cc[q8*8+6], __uint_as_float(w3 << 16),          ah);
          ah = fmaf(cc[q8*8+7], __uint_as_float(w3 & 0xFFFF0000u),  ah);
        }
        hv = ln(xb + ah);                                 // B5,B6
      }
    }

    // Phase 4: hist[t] := h (area_bf row for dots; own histT row for Ah —
    // same-thread write/read, needs no barrier)
    if (t < T_STEPS - 1) {
      const ushort h16 = (ushort)bf16cvt(hv);
      area_bf[t][r] = h16;
      histT[r][t]   = h16;
    }
  }

  out[(size_t)b * DH + r] = hv;
}

extern "C" void kernel_launch(void* const* d_in, const int* in_sizes, int n_in,
                              void* d_out, int out_size, void* d_ws, size_t ws_size,
                              hipStream_t stream) {
  const float* z     = (const float*)d_in[0];  // [T,B,DG]
  const float* W_h   = (const float*)d_in[1];  // [DH,DH]
  const float* W_g   = (const float*)d_in[2];  // [DH,DG]
  const float* b_h   = (const float*)d_in[3];  // [DH]
  const float* gamma = (const float*)d_in[4];  // [DH]
  const float* beta  = (const float*)d_in[5];  // [DH]
  float* out = (float*)d_out;                  // [B,DH]

  uint4* Wp = (uint4*)d_ws;                    // 512 KB packed W_h

  pack_kernel<<<dim3(64), dim3(512), 0, stream>>>(W_h, Wp);
  rnn_kernel<<<dim3(BATCH), dim3(512), 0, stream>>>(Wp, z, W_g, b_h,
                                                    gamma, beta, out);
}